// Round 1
// baseline (143.238 us; speedup 1.0000x reference)
//
#include <hip/hip_runtime.h>
#include <hip/hip_bf16.h>

#define MB_    32
#define ATOM_  64
#define HID_   64
#define NRBF_  300
#define NKK1   10          // ceil(300/32) K-steps for GEMM1 (padded to 320)
#define GAMMA_ 10.0f
#define RES_   0.1f

typedef __attribute__((ext_vector_type(8))) short  short8;
typedef __attribute__((ext_vector_type(4))) short  short4v;
typedef __attribute__((ext_vector_type(4))) float  floatx4;

__device__ __forceinline__ unsigned short f2bf(float f) {
    union { float f; unsigned u; } v; v.f = f;
    unsigned r = v.u + 0x7fffu + ((v.u >> 16) & 1u);   // round-to-nearest-even
    return (unsigned short)(r >> 16);
}
__device__ __forceinline__ float bf2f(unsigned short s) {
    union { unsigned u; float f; } v; v.u = ((unsigned)s) << 16;
    return v.f;
}
__device__ __forceinline__ float softplus_f(float x) {
    return fmaxf(x, 0.f) + __logf(1.f + __expf(-fabsf(x)));
}

#define MFMA16(a, b, c) __builtin_amdgcn_mfma_f32_16x16x32_bf16((a), (b), (c), 0, 0, 0)

__global__ __launch_bounds__(256, 2)
void schnet_fused(const float* __restrict__ x,   const float* __restrict__ dist,
                  const float* __restrict__ W1,  const float* __restrict__ b1,
                  const float* __restrict__ W2,  const float* __restrict__ b2,
                  const float* __restrict__ W3,  const float* __restrict__ b3,
                  const float* __restrict__ Wd1, const float* __restrict__ bd1,
                  const float* __restrict__ Wd2, const float* __restrict__ bd2,
                  float* __restrict__ out)
{
    const int m    = blockIdx.x >> 6;
    const int j    = blockIdx.x & 63;
    const int tid  = threadIdx.x;
    const int lane = tid & 63;
    const int w    = tid >> 6;       // wave id 0..3 -> row strip 16w..16w+15
    const int l15  = lane & 15;
    const int quad = lane >> 4;

    // ---- LDS (total 79616 B -> 2 blocks/CU) ----
    __shared__ short sB1 [NKK1 * 4 * 64 * 8]; // 40960 B: Wd1 in B-frag order (bf16, K padded to 320)
    __shared__ short sBW1[2 * 4 * 64 * 8];    //  8192 B: W1  in B-frag order
    __shared__ short sB2 [2 * 4 * 64 * 8];    //  8192 B: Wd2 in B-frag order
    __shared__ short sX  [64 * 64];           //  8192 B: x[m] bf16 row-major; reused as f1
    __shared__ short sV1 [64 * 64];           //  8192 B: v1 bf16 row-major [i][c]
    __shared__ short sA  [64 * 32];           //  4096 B: on-the-fly RBF tile [i][k%32]
    __shared__ float sD  [64];                //   256 B: dist[m, :, j]
    __shared__ float sRed[4 * 64];            //  1024 B: cross-wave partials
    __shared__ float sAgg[64];                //   256 B
    __shared__ float sU  [64];                //   256 B

    // ---- stage x[m] -> sX (bf16, row-major [i][c]) ----
    const float* xm = x + m * (ATOM_ * HID_);
    for (int e = tid; e < ATOM_ * HID_ / 4; e += 256) {
        float4 v = ((const float4*)xm)[e];
        short4v s;
        s.x = (short)f2bf(v.x); s.y = (short)f2bf(v.y);
        s.z = (short)f2bf(v.z); s.w = (short)f2bf(v.w);
        *(short4v*)(sX + e * 4) = s;
    }
    // ---- stage dist column: sD[i] = dist[m, i, j] ----
    if (tid < 64) sD[tid] = dist[(m * ATOM_ + tid) * ATOM_ + j];

    // ---- stage weights into B-fragment order (bf16) ----
    // slot g = (kk*4 + t)*64 + lane; holds W[16t + (lane&15)][kk*32 + (lane>>4)*8 + jj], jj=0..7
    auto stageB = [&](const float* __restrict__ Wsrc, int Kreal, int nkk, short* dst) {
        const int groups = nkk * 4 * 64;
        for (int g = tid; g < groups; g += 256) {
            int l  = g & 63;
            int t  = (g >> 6) & 3;
            int kk = g >> 8;
            int row = 16 * t + (l & 15);
            int r0  = kk * 32 + ((l >> 4) << 3);
            short8 vv;
            if (r0 + 8 <= Kreal) {
                const float4* p = (const float4*)(Wsrc + row * Kreal + r0);
                float4 a = p[0], b = p[1];
                vv[0] = (short)f2bf(a.x); vv[1] = (short)f2bf(a.y);
                vv[2] = (short)f2bf(a.z); vv[3] = (short)f2bf(a.w);
                vv[4] = (short)f2bf(b.x); vv[5] = (short)f2bf(b.y);
                vv[6] = (short)f2bf(b.z); vv[7] = (short)f2bf(b.w);
            } else {
                #pragma unroll
                for (int jj = 0; jj < 8; ++jj) {
                    int r = r0 + jj;
                    float val = (r < Kreal) ? Wsrc[row * Kreal + r] : 0.f;
                    vv[jj] = (short)f2bf(val);
                }
            }
            *(short8*)(dst + g * 8) = vv;
        }
    };
    stageB(W1,  64,  2,    sBW1);
    stageB(Wd2, 64,  2,    sB2);
    stageB(Wd1, NRBF_, NKK1, sB1);
    __syncthreads();

    floatx4 zero = {0.f, 0.f, 0.f, 0.f};

    // ---- GEMM0: v1 = x[m] @ W1^T + b1  (C rows = wave strip) ----
    floatx4 acc[4];
    #pragma unroll
    for (int t = 0; t < 4; ++t) acc[t] = zero;
    #pragma unroll
    for (int kk = 0; kk < 2; ++kk) {
        short8 a = *(const short8*)(sX + (16 * w + l15) * 64 + kk * 32 + quad * 8);
        #pragma unroll
        for (int t = 0; t < 4; ++t) {
            short8 b = *(const short8*)(sBW1 + ((kk * 4 + t) * 64 + lane) * 8);
            acc[t] = MFMA16(a, b, acc[t]);
        }
    }
    {
        float b1v[4];
        #pragma unroll
        for (int t = 0; t < 4; ++t) b1v[t] = b1[16 * t + l15];
        #pragma unroll
        for (int t = 0; t < 4; ++t)
            #pragma unroll
            for (int reg = 0; reg < 4; ++reg)
                sV1[(16 * w + quad * 4 + reg) * 64 + 16 * t + l15] = (short)f2bf(acc[t][reg] + b1v[t]);
    }

    // ---- GEMM1: f1_pre = RBF(dist) @ Wd1^T, RBF generated on the fly ----
    #pragma unroll
    for (int t = 0; t < 4; ++t) acc[t] = zero;
    const int gi = tid >> 2;          // row 0..63 this thread generates
    const int gk = (tid & 3) * 8;     // k-offset within 32-tile
    __syncthreads();                  // sV1 writes visible; sD/sB1 staged
    const float di = sD[gi];
    for (int kk = 0; kk < NKK1; ++kk) {
        short8 vv;
        #pragma unroll
        for (int jj = 0; jj < 8; ++jj) {
            int r = kk * 32 + gk + jj;
            float t_ = di - RES_ * (float)r;
            float e  = __expf(-GAMMA_ * t_ * t_);
            vv[jj] = (r < NRBF_) ? (short)f2bf(e) : (short)0;
        }
        __syncthreads();              // WAR: previous step's A-frag reads done
        *(short8*)(sA + gi * 32 + gk) = vv;
        __syncthreads();              // RAW: tile visible
        short8 a = *(const short8*)(sA + (16 * w + l15) * 32 + quad * 8);
        #pragma unroll
        for (int t = 0; t < 4; ++t) {
            short8 b = *(const short8*)(sB1 + ((kk * 4 + t) * 64 + lane) * 8);
            acc[t] = MFMA16(a, b, acc[t]);
        }
    }

    // ---- f1 = softplus(. + bd1) -> sX (reuse) bf16 row-major [i][h] ----
    {
        float bd1v[4];
        #pragma unroll
        for (int t = 0; t < 4; ++t) bd1v[t] = bd1[16 * t + l15];
        #pragma unroll
        for (int t = 0; t < 4; ++t)
            #pragma unroll
            for (int reg = 0; reg < 4; ++reg) {
                float s_ = softplus_f(acc[t][reg] + bd1v[t]);
                sX[(16 * w + quad * 4 + reg) * 64 + 16 * t + l15] = (short)f2bf(s_);
            }
    }
    __syncthreads();

    // ---- GEMM2: f2_pre = f1 @ Wd2^T ----
    #pragma unroll
    for (int t = 0; t < 4; ++t) acc[t] = zero;
    #pragma unroll
    for (int kk = 0; kk < 2; ++kk) {
        short8 a = *(const short8*)(sX + (16 * w + l15) * 64 + kk * 32 + quad * 8);
        #pragma unroll
        for (int t = 0; t < 4; ++t) {
            short8 b = *(const short8*)(sB2 + ((kk * 4 + t) * 64 + lane) * 8);
            acc[t] = MFMA16(a, b, acc[t]);
        }
    }

    // ---- f2 = softplus(. + bd2); agg[c] = sum_i v1[i][c] * f2[i][c] ----
    {
        float bd2v[4];
        #pragma unroll
        for (int t = 0; t < 4; ++t) bd2v[t] = bd2[16 * t + l15];
        #pragma unroll
        for (int t = 0; t < 4; ++t) {
            float cs = 0.f;
            #pragma unroll
            for (int reg = 0; reg < 4; ++reg) {
                int i = 16 * w + quad * 4 + reg;
                float f2v = softplus_f(acc[t][reg] + bd2v[t]);
                cs += f2v * bf2f((unsigned short)sV1[i * 64 + 16 * t + l15]);
            }
            cs += __shfl_xor(cs, 16, 64);   // sum over quads (rows within wave strip)
            cs += __shfl_xor(cs, 32, 64);
            if (quad == 0) sRed[w * 64 + 16 * t + l15] = cs;
        }
    }
    __syncthreads();
    if (tid < 64)
        sAgg[tid] = sRed[tid] + sRed[64 + tid] + sRed[128 + tid] + sRed[192 + tid];
    __syncthreads();

    // ---- stage C: v2 = sp(agg @ W2^T + b2); v3 = v2 @ W3^T + b3; out = x + v3 ----
    {
        int o = tid & 63, p = tid >> 6;
        float s_ = 0.f;
        #pragma unroll
        for (int c = 0; c < 16; ++c) s_ += sAgg[16 * p + c] * W2[o * 64 + 16 * p + c];
        sRed[p * 64 + o] = s_;
    }
    __syncthreads();
    if (tid < 64) {
        float v_ = sRed[tid] + sRed[64 + tid] + sRed[128 + tid] + sRed[192 + tid] + b2[tid];
        sU[tid] = softplus_f(v_);
    }
    __syncthreads();
    {
        int o = tid & 63, p = tid >> 6;
        float s_ = 0.f;
        #pragma unroll
        for (int c = 0; c < 16; ++c) s_ += sU[16 * p + c] * W3[o * 64 + 16 * p + c];
        sRed[p * 64 + o] = s_;
    }
    __syncthreads();
    if (tid < 64) {
        float v_ = sRed[tid] + sRed[64 + tid] + sRed[128 + tid] + sRed[192 + tid] + b3[tid];
        out[(m * ATOM_ + j) * HID_ + tid] = v_ + x[(m * ATOM_ + j) * HID_ + tid];
    }
}

extern "C" void kernel_launch(void* const* d_in, const int* in_sizes, int n_in,
                              void* d_out, int out_size, void* d_ws, size_t ws_size,
                              hipStream_t stream) {
    const float* x   = (const float*)d_in[0];
    const float* dist= (const float*)d_in[1];
    const float* W1  = (const float*)d_in[2];
    const float* b1  = (const float*)d_in[3];
    const float* W2  = (const float*)d_in[4];
    const float* b2  = (const float*)d_in[5];
    const float* W3  = (const float*)d_in[6];
    const float* b3  = (const float*)d_in[7];
    const float* Wd1 = (const float*)d_in[8];
    const float* bd1 = (const float*)d_in[9];
    const float* Wd2 = (const float*)d_in[10];
    const float* bd2 = (const float*)d_in[11];
    float* out = (float*)d_out;
    (void)in_sizes; (void)n_in; (void)out_size; (void)d_ws; (void)ws_size;

    schnet_fused<<<dim3(MB_ * ATOM_), dim3(256), 0, stream>>>(
        x, dist, W1, b1, W2, b2, W3, b3, Wd1, bd1, Wd2, bd2, out);
}

// Round 2
// 104.939 us; speedup vs baseline: 1.3650x; 1.3650x over previous
//
#include <hip/hip_runtime.h>
#include <math.h>

#define MB_    32
#define ATOM_  64
#define HID_   64
#define NRBF_  300
#define GAMMA_ 10.0f
#define RES_   0.1f

// filter table: f2(d) sampled at TPTS points, step TSTEP, domain [0, 10]
#define TPTS      2001
#define TSTEP     0.005f
#define INV_TSTEP 200.0f

// workspace layout (float offsets)
#define T_OFF   0
#define T_SZ    (TPTS * 64)          // 128064
#define V1_OFF  (T_OFF + T_SZ)       // 128064
#define V1_SZ   (MB_ * 64 * 64)      // 131072
#define W2T_OFF (V1_OFF + V1_SZ)     // 259136
#define W3T_OFF (W2T_OFF + 4096)     // 263232
// total 267328 floats = 1,069,312 bytes of d_ws

__device__ __forceinline__ float sp_f(float x) {
    return fmaxf(x, 0.f) + log1pf(__expf(-fabsf(x)));
}

// ---------------------------------------------------------------------------
// prep: blocks [0,32)   -> v1[m] = x[m] @ W1^T + b1            (f32, exact)
//       blocks [32,533) -> filter table rows (4 d-samples each)
//       block  533      -> W2^T, W3^T for coalesced tail reads
// ---------------------------------------------------------------------------
__global__ __launch_bounds__(256)
void schnet_prep(const float* __restrict__ x,   const float* __restrict__ W1,
                 const float* __restrict__ b1,  const float* __restrict__ W2,
                 const float* __restrict__ W3,  const float* __restrict__ Wd1,
                 const float* __restrict__ bd1, const float* __restrict__ Wd2,
                 const float* __restrict__ bd2, float* __restrict__ ws)
{
    __shared__ float smem[8256];     // 33 KB, unioned between branches
    const int tid = threadIdx.x;
    const int b   = blockIdx.x;

    if (b < MB_) {
        // ---- v1 = x[m] @ W1^T + b1 ----
        float* sx = smem;            // [64][64]
        float* sw = smem + 4096;     // W1^T, [c][o] stride 65 (bank-conflict-free)
        const float* xm = x + b * 4096;
        for (int e = tid; e < 1024; e += 256)
            ((float4*)sx)[e] = ((const float4*)xm)[e];
        for (int e = tid; e < 4096; e += 256) {
            int o = e >> 6, c = e & 63;
            sw[c * 65 + o] = W1[e];
        }
        __syncthreads();
        const int o = tid & 63, p = tid >> 6;
        const float bo = b1[o];
        for (int ii = 0; ii < 16; ++ii) {
            const int i = p * 16 + ii;
            float acc = bo;
            #pragma unroll
            for (int c = 0; c < 64; ++c)
                acc = fmaf(sx[i * 64 + c], sw[c * 65 + o], acc);  // sx broadcast, sw coalesced
            ws[V1_OFF + (b * 64 + i) * 64 + o] = acc;
        }
    } else if (b < MB_ + 501) {
        // ---- table: 4 d-samples per block (subgroup = wave) ----
        float* rbf = smem;           // [4][320] (300 real + zero pad)
        float* u   = smem + 1280;    // [4][64]
        float* wt  = smem + 1536;    // [64][65] chunk buffer (Wd1^T then Wd2^T)
        const int sub = tid >> 6, lane = tid & 63;
        const int s = (b - MB_) * 4 + sub;
        const bool live = (s < TPTS);
        const float d = live ? s * TSTEP : 0.f;

        if (live) {
            for (int r = lane; r < NRBF_; r += 64) {
                float t = fmaf(-RES_, (float)r, d);
                rbf[sub * 320 + r] = __expf(-GAMMA_ * t * t);
            }
            if (lane < 20) rbf[sub * 320 + 300 + lane] = 0.f;   // pad (avoid NaN*0)
        }
        float a = live ? bd1[lane] : 0.f;
        for (int r0 = 0; r0 < 320; r0 += 64) {
            __syncthreads();         // WAR on wt
            for (int e = tid; e < 4096; e += 256) {
                int h = e >> 6, rr = e & 63;
                int r = r0 + rr;
                wt[rr * 65 + h] = (r < NRBF_) ? Wd1[h * NRBF_ + r] : 0.f;
            }
            __syncthreads();         // RAW on wt
            if (live) {
                #pragma unroll
                for (int rr = 0; rr < 64; ++rr)
                    a = fmaf(wt[rr * 65 + lane], rbf[sub * 320 + r0 + rr], a);
            }
        }
        if (live) u[sub * 64 + lane] = sp_f(a);
        __syncthreads();
        // stage Wd2^T into wt (reuse)
        for (int e = tid; e < 4096; e += 256) {
            int o = e >> 6, c = e & 63;
            wt[c * 65 + o] = Wd2[e];
        }
        __syncthreads();
        if (live) {
            float a2 = bd2[lane];
            #pragma unroll
            for (int h1 = 0; h1 < 64; ++h1)
                a2 = fmaf(wt[h1 * 65 + lane], u[sub * 64 + h1], a2);
            ws[T_OFF + s * 64 + lane] = sp_f(a2);
        }
    } else {
        // ---- transpose W2, W3 ----
        for (int e = tid; e < 4096; e += 256) {
            int o = e >> 6, c = e & 63;
            ws[W2T_OFF + c * 64 + o] = W2[e];
            ws[W3T_OFF + c * 64 + o] = W3[e];
        }
    }
}

// ---------------------------------------------------------------------------
// main: one block per (m, j).  agg[c] = sum_i v1[m,i,c] * lerp(T, d_ij)[c]
//       then v2 = sp(agg @ W2^T + b2); out = x + v2 @ W3^T + b3
// ---------------------------------------------------------------------------
__global__ __launch_bounds__(256)
void schnet_main(const float* __restrict__ x, const float* __restrict__ dist,
                 const float* __restrict__ b2, const float* __restrict__ b3,
                 const float* __restrict__ ws, float* __restrict__ out)
{
    __shared__ float sD[64];
    __shared__ float sRed[4 * 64];
    const int m   = blockIdx.x >> 6;
    const int j   = blockIdx.x & 63;
    const int tid = threadIdx.x;
    const int c   = tid & 63;        // channel this thread owns (lane)
    const int p   = tid >> 6;        // wave = i-quarter

    if (tid < 64) sD[tid] = dist[(m * ATOM_ + tid) * ATOM_ + j];
    __syncthreads();

    const float* Tb  = ws + T_OFF;
    const float* v1m = ws + V1_OFF + (m * 64 + p * 16) * 64;
    float acc = 0.f;
    #pragma unroll
    for (int ii = 0; ii < 16; ++ii) {
        float d  = sD[p * 16 + ii];                 // LDS broadcast
        float f  = d * INV_TSTEP;
        int   s  = min((int)f, TPTS - 2);
        float fr = f - (float)s;
        const float* Tr = Tb + s * 64;
        float t0 = Tr[c], t1 = Tr[64 + c];          // coalesced 256B rows
        float f2v = fmaf(fr, t1 - t0, t0);
        acc = fmaf(f2v, v1m[ii * 64 + c], acc);     // coalesced, L1/L2-hit
    }
    sRed[p * 64 + c] = acc;
    __syncthreads();
    if (tid < 64)
        sD[tid] = sRed[tid] + sRed[64 + tid] + sRed[128 + tid] + sRed[192 + tid];
    __syncthreads();

    // v2_pre = agg @ W2^T : thread (o=c, quarter=p) does 16 MACs, coalesced W2T
    {
        const float* W2t = ws + W2T_OFF;
        float s_ = 0.f;
        #pragma unroll
        for (int cc = 0; cc < 16; ++cc)
            s_ = fmaf(sD[16 * p + cc], W2t[(16 * p + cc) * 64 + c], s_);
        sRed[p * 64 + c] = s_;
    }
    __syncthreads();
    if (tid < 64)
        sD[tid] = sp_f(sRed[tid] + sRed[64 + tid] + sRed[128 + tid] + sRed[192 + tid] + b2[tid]);
    __syncthreads();
    {
        const float* W3t = ws + W3T_OFF;
        float s_ = 0.f;
        #pragma unroll
        for (int cc = 0; cc < 16; ++cc)
            s_ = fmaf(sD[16 * p + cc], W3t[(16 * p + cc) * 64 + c], s_);
        sRed[p * 64 + c] = s_;
    }
    __syncthreads();
    if (tid < 64) {
        float v_ = sRed[tid] + sRed[64 + tid] + sRed[128 + tid] + sRed[192 + tid] + b3[tid];
        out[(m * ATOM_ + j) * HID_ + tid] = v_ + x[(m * ATOM_ + j) * HID_ + tid];
    }
}

extern "C" void kernel_launch(void* const* d_in, const int* in_sizes, int n_in,
                              void* d_out, int out_size, void* d_ws, size_t ws_size,
                              hipStream_t stream) {
    const float* x   = (const float*)d_in[0];
    const float* dist= (const float*)d_in[1];
    const float* W1  = (const float*)d_in[2];
    const float* b1  = (const float*)d_in[3];
    const float* W2  = (const float*)d_in[4];
    const float* b2  = (const float*)d_in[5];
    const float* W3  = (const float*)d_in[6];
    const float* b3  = (const float*)d_in[7];
    const float* Wd1 = (const float*)d_in[8];
    const float* bd1 = (const float*)d_in[9];
    const float* Wd2 = (const float*)d_in[10];
    const float* bd2 = (const float*)d_in[11];
    float* out = (float*)d_out;
    float* ws  = (float*)d_ws;
    (void)in_sizes; (void)n_in; (void)out_size; (void)ws_size;
    // needs ~1.07 MB of d_ws (table + v1 + W2^T/W3^T)

    schnet_prep<<<dim3(MB_ + 501 + 1), dim3(256), 0, stream>>>(
        x, W1, b1, W2, W3, Wd1, bd1, Wd2, bd2, ws);
    schnet_main<<<dim3(MB_ * ATOM_), dim3(256), 0, stream>>>(
        x, dist, b2, b3, ws, out);
}